// Round 1
// baseline (697.751 us; speedup 1.0000x reference)
//
#include <hip/hip_runtime.h>

#define D 256
#define H 256
#define O 24
#define R 32   // rows per block

// Fused 3-layer MLP + top-6-of-22 mask.
// Block: 256 threads = 4 row-groups (8 rows each) x 64 col-groups (4 cols each).
// LDS: bufA (x tile, later h2) + bufB (h1, later logits+selmask) = exactly 64 KB.
__global__ __launch_bounds__(256, 2) void fused_mlp_topk(
    const float* __restrict__ x,  const float* __restrict__ W1, const float* __restrict__ b1,
    const float* __restrict__ W2, const float* __restrict__ b2,
    const float* __restrict__ W3, const float* __restrict__ b3,
    float* __restrict__ out)
{
    __shared__ float bufA[R][D];   // x tile, then h2
    __shared__ float bufB[R][H];   // h1; later overlaid with logits + selmask

    float (*logits)[O] = (float (*)[O])(&bufB[0][0]);
    unsigned int* selmask = (unsigned int*)(&bufB[0][0] + R * O);

    const int t = threadIdx.x;
    const long row0 = (long)blockIdx.x * R;

    // ---- stage x tile: 32 rows x 256 cols, coalesced float4 ----
    {
        const int tt = t & 63;
        const int rr = t >> 6;
        #pragma unroll
        for (int r = rr; r < R; r += 4) {
            float4 v = *(const float4*)(x + (row0 + r) * D + 4 * tt);
            *(float4*)(&bufA[r][4 * tt]) = v;
        }
    }
    __syncthreads();

    const int tt = t & 63;   // column group: cols 4*tt .. 4*tt+3
    const int g  = t >> 6;   // row group:  rows 8*g .. 8*g+7
    const int c0 = tt * 4;
    const int r0 = g * 8;

    // ---- Layer 1: bufB = relu(bufA @ W1 + b1) ----
    {
        float acc[8][4];
        float4 bias = *(const float4*)(b1 + c0);
        #pragma unroll
        for (int r = 0; r < 8; ++r) {
            acc[r][0] = bias.x; acc[r][1] = bias.y; acc[r][2] = bias.z; acc[r][3] = bias.w;
        }
        for (int k = 0; k < D; ++k) {
            float4 w = *(const float4*)(W1 + (size_t)k * H + c0);
            #pragma unroll
            for (int r = 0; r < 8; ++r) {
                float xv = bufA[r0 + r][k];   // wave-uniform address -> LDS broadcast
                acc[r][0] = fmaf(xv, w.x, acc[r][0]);
                acc[r][1] = fmaf(xv, w.y, acc[r][1]);
                acc[r][2] = fmaf(xv, w.z, acc[r][2]);
                acc[r][3] = fmaf(xv, w.w, acc[r][3]);
            }
        }
        #pragma unroll
        for (int r = 0; r < 8; ++r) {
            float4 v = make_float4(fmaxf(acc[r][0], 0.f), fmaxf(acc[r][1], 0.f),
                                   fmaxf(acc[r][2], 0.f), fmaxf(acc[r][3], 0.f));
            *(float4*)(&bufB[r0 + r][c0]) = v;
        }
    }
    __syncthreads();

    // ---- Layer 2: bufA = relu(bufB @ W2 + b2)  (x tile is dead) ----
    {
        float acc[8][4];
        float4 bias = *(const float4*)(b2 + c0);
        #pragma unroll
        for (int r = 0; r < 8; ++r) {
            acc[r][0] = bias.x; acc[r][1] = bias.y; acc[r][2] = bias.z; acc[r][3] = bias.w;
        }
        for (int k = 0; k < H; ++k) {
            float4 w = *(const float4*)(W2 + (size_t)k * H + c0);
            #pragma unroll
            for (int r = 0; r < 8; ++r) {
                float hv = bufB[r0 + r][k];
                acc[r][0] = fmaf(hv, w.x, acc[r][0]);
                acc[r][1] = fmaf(hv, w.y, acc[r][1]);
                acc[r][2] = fmaf(hv, w.z, acc[r][2]);
                acc[r][3] = fmaf(hv, w.w, acc[r][3]);
            }
        }
        #pragma unroll
        for (int r = 0; r < 8; ++r) {
            float4 v = make_float4(fmaxf(acc[r][0], 0.f), fmaxf(acc[r][1], 0.f),
                                   fmaxf(acc[r][2], 0.f), fmaxf(acc[r][3], 0.f));
            *(float4*)(&bufA[r0 + r][c0]) = v;
        }
    }
    __syncthreads();

    // ---- Layer 3: logits[r][j] = h2[r] . W3[:,j] + b3[j]  (768 dots of length 256) ----
    // NOTE: logits overlays bufB (h1 is dead); reads come only from bufA.
    for (int id = t; id < R * O; id += 256) {
        const int r = id / O;
        const int j = id - r * O;
        float acc = b3[j];
        for (int k = 0; k < H; ++k)
            acc = fmaf(bufA[r][k], W3[(size_t)k * O + j], acc);
        logits[r][j] = acc;
    }
    __syncthreads();

    // ---- top-6 of the 22 selected columns (cols != 0,12), one thread per row ----
    if (t < R) {
        float v[22];
        #pragma unroll
        for (int i = 0; i < 22; ++i) {
            const int j = (i < 11) ? (i + 1) : (i + 2);
            v[i] = logits[t][j];
        }
        unsigned taken = 0u;
        unsigned cm = 1u | (1u << 12);   // columns 0 and 12 forced to 1
        for (int kk = 0; kk < 6; ++kk) {
            float best = -3.4e38f; int bi = 0;
            #pragma unroll
            for (int i = 0; i < 22; ++i) {
                // ascending scan + strict '>' => lowest index wins ties (matches lax.top_k)
                if (!((taken >> i) & 1u) && v[i] > best) { best = v[i]; bi = i; }
            }
            taken |= 1u << bi;
            cm |= 1u << ((bi < 11) ? (bi + 1) : (bi + 2));
        }
        selmask[t] = cm;
    }
    __syncthreads();

    // ---- write mask (coalesced) ----
    for (int id = t; id < R * O; id += 256) {
        const int r = id / O;
        const int j = id - r * O;
        out[row0 * O + id] = ((selmask[r] >> j) & 1u) ? 1.0f : 0.0f;
    }
}

extern "C" void kernel_launch(void* const* d_in, const int* in_sizes, int n_in,
                              void* d_out, int out_size, void* d_ws, size_t ws_size,
                              hipStream_t stream) {
    const float* x  = (const float*)d_in[0];
    const float* W1 = (const float*)d_in[1];
    const float* b1 = (const float*)d_in[2];
    const float* W2 = (const float*)d_in[3];
    const float* b2 = (const float*)d_in[4];
    const float* W3 = (const float*)d_in[5];
    const float* b3 = (const float*)d_in[6];
    float* out = (float*)d_out;

    const int B = in_sizes[0] / D;       // 131072
    const int nblk = B / R;              // 4096
    hipLaunchKernelGGL(fused_mlp_topk, dim3(nblk), dim3(256), 0, stream,
                       x, W1, b1, W2, b2, W3, b3, out);
}